// Round 9
// baseline (183.560 us; speedup 1.0000x reference)
//
#include <hip/hip_runtime.h>
#include <hip/hip_bf16.h>
#include <math.h>

#define B_ 16
#define D_ 64
#define T_ 4096
#define K_ 1024
#define BT_ (B_*T_)

// output layout (flat f32, concatenated in return order)
#define ZQ_OFF   0
#define LOSS_OFF 4194304
#define IDX_OFF  4194305
#define PERP_OFF 4259841
#define HIST_OFF 4259842

typedef __attribute__((ext_vector_type(8))) short bf16x8;
typedef __attribute__((ext_vector_type(4))) float f32x4;

__device__ __forceinline__ unsigned umin_(unsigned a, unsigned b){ return a < b ? a : b; }
__device__ __forceinline__ unsigned umax_(unsigned a, unsigned b){ return a > b ? a : b; }

__device__ __forceinline__ ushort f2bf(float x) {
  __hip_bfloat16 h = __float2bfloat16(x);
  return *(ushort*)&h;
}
__device__ __forceinline__ float bf2f(ushort u) {
  __hip_bfloat16 h; *(ushort*)&h = u;
  return __bfloat162float(h);
}

// ---- prep: zero counters + emb f32 -> (ebh, ebl) bf16 split + e_sq ----
__global__ __launch_bounds__(256) void prep_kernel(
    const float* __restrict__ emb, int* __restrict__ zero_ws,
    float* __restrict__ e_sq, ushort* __restrict__ ebh, ushort* __restrict__ ebl) {
  const int tid = blockIdx.x * 256 + threadIdx.x;
  if (tid < 1026) zero_ws[tid] = 0;   // counts[1024] + commit (+spare)
  const int k = tid >> 2, q = tid & 3;
  const float4* p = (const float4*)(emb + (size_t)k * D_ + q * 16);
  bf16x8 vh[2], vl[2];
  float s = 0.f;
#pragma unroll
  for (int i = 0; i < 4; ++i) {
    float4 v = p[i];
    float xs[4] = {v.x, v.y, v.z, v.w};
#pragma unroll
    for (int j = 0; j < 4; ++j) {
      float x = xs[j];
      ushort hb = f2bf(x);
      ushort lb = f2bf(x - bf2f(hb));
      vh[i >> 1][(i & 1) * 4 + j] = (short)hb;
      vl[i >> 1][(i & 1) * 4 + j] = (short)lb;
      s = fmaf(x, x, s);
    }
  }
  size_t off = (size_t)k * D_ + q * 16;
  *(bf16x8*)(ebh + off) = vh[0];
  *(bf16x8*)(ebh + off + 8) = vh[1];
  *(bf16x8*)(ebl + off) = vl[0];
  *(bf16x8*)(ebl + off + 8) = vl[1];
  s += __shfl_xor(s, 1, 64);
  s += __shfl_xor(s, 2, 64);
  if (q == 0) e_sq[k] = s;
}

__device__ double dist64row(const float* __restrict__ zb, int r,
                            const float* __restrict__ emb, int k) {
  double s = 0.0, dot = 0.0;
#pragma unroll
  for (int d = 0; d < D_; ++d) {
    double e = (double)emb[(size_t)k * D_ + d];
    double x = (double)zb[(size_t)d * T_ + r];
    s += e * e;
    dot += x * e;
  }
  return s - 2.0 * dot;
}

// ---- main: 32 rows/block, 4 waves x 256-code quadrant, MFMA bf16-split ----
// Occupancy probe: pin EXACTLY 4 waves/EU (VGPR budget 128). The (min,max)
// form prevents the round-6 failure where min-only let the allocator drop to
// 84 VGPR and spill ~90 regs (WRITE_SIZE 18.6->66 MB, 2x slower).
__global__ __launch_bounds__(256)
__attribute__((amdgpu_waves_per_eu(4, 4)))
void vq_mfma(
    const float* __restrict__ z_e, const float* __restrict__ emb_f32,
    const float* __restrict__ e_sq, const ushort* __restrict__ ebh,
    const ushort* __restrict__ ebl, float* __restrict__ out,
    float* __restrict__ commit_ws, int* __restrict__ counts) {
  __shared__ ushort Ah[32 * 64];
  __shared__ ushort Al[32 * 64];
  __shared__ unsigned mrg1[4][32];
  __shared__ unsigned mrg2[4][32];
  __shared__ int idx_sh[32];
  __shared__ float cred[256];

  const int tid = threadIdx.x;
  const int lane = tid & 63, wave = tid >> 6;
  const int b = blockIdx.x >> 7;
  const int t0 = (blockIdx.x & 127) << 5;
  const float* zbase = z_e + ((size_t)b * D_) * T_ + t0;

  // Phase 0: stage A tile (32 rows x 64 d) as bf16 hi/lo, XOR-swizzled rows
  {
    const int r = tid & 31, d0 = (tid >> 5) * 8;
    bf16x8 vh, vl;
#pragma unroll
    for (int j = 0; j < 8; ++j) {
      float x = zbase[(size_t)(d0 + j) * T_ + r];
      ushort hb = f2bf(x);
      vh[j] = (short)hb;
      vl[j] = (short)f2bf(x - bf2f(hb));
    }
    const int off = (r * 128 + d0 * 2) ^ ((r & 7) << 4);  // byte offset
    *(bf16x8*)((char*)Ah + off) = vh;
    *(bf16x8*)((char*)Al + off) = vl;
  }
  __syncthreads();

  // A fragments to registers (reused across all 16 slabs): [rowfrag][kstep]
  bf16x8 afh[2][2], afl[2][2];
  {
    const int ar = lane & 15;
    const int aks = (lane >> 4) * 8;
#pragma unroll
    for (int f = 0; f < 2; ++f)
#pragma unroll
      for (int ks = 0; ks < 2; ++ks) {
        const int row = f * 16 + ar;
        const int col = ks * 32 + aks;
        const int off = (row * 128 + col * 2) ^ ((row & 7) << 4);
        afh[f][ks] = *(bf16x8*)((char*)Ah + off);
        afl[f][ks] = *(bf16x8*)((char*)Al + off);
      }
  }

  const int cw0 = wave * 256;  // wave's code base (wave-uniform)
  const size_t boff = (size_t)(cw0 + (lane & 15)) * D_ + (lane >> 4) * 8;

  unsigned b1[2][4], b2[2][4];
#pragma unroll
  for (int f = 0; f < 2; ++f)
#pragma unroll
    for (int r = 0; r < 4; ++r) { b1[f][r] = 0xFFFFFFFFu; b2[f][r] = 0xFFFFFFFFu; }

  bf16x8 cbh[2][2], cbl[2][2];
  float cesq[2];
#define LOADB(s, buf)                                                   \
  { size_t o = boff + (size_t)(s) * 16 * D_;                            \
    cbh[buf][0] = *(const bf16x8*)(ebh + o);                            \
    cbh[buf][1] = *(const bf16x8*)(ebh + o + 32);                       \
    cbl[buf][0] = *(const bf16x8*)(ebl + o);                            \
    cbl[buf][1] = *(const bf16x8*)(ebl + o + 32);                       \
    cesq[buf] = e_sq[cw0 + (s) * 16 + (lane & 15)]; }

  LOADB(0, 0);
#pragma unroll
  for (int s = 0; s < 16; ++s) {
    const int cur = s & 1, nxt = cur ^ 1;
    if (s < 15) LOADB(s + 1, nxt);
    f32x4 a0 = {0.f, 0.f, 0.f, 0.f}, a1 = {0.f, 0.f, 0.f, 0.f};
    // hi*hi (both ksteps)
    a0 = __builtin_amdgcn_mfma_f32_16x16x32_bf16(afh[0][0], cbh[cur][0], a0, 0, 0, 0);
    a1 = __builtin_amdgcn_mfma_f32_16x16x32_bf16(afh[1][0], cbh[cur][0], a1, 0, 0, 0);
    a0 = __builtin_amdgcn_mfma_f32_16x16x32_bf16(afh[0][1], cbh[cur][1], a0, 0, 0, 0);
    a1 = __builtin_amdgcn_mfma_f32_16x16x32_bf16(afh[1][1], cbh[cur][1], a1, 0, 0, 0);
    // lo*hi
    a0 = __builtin_amdgcn_mfma_f32_16x16x32_bf16(afl[0][0], cbh[cur][0], a0, 0, 0, 0);
    a1 = __builtin_amdgcn_mfma_f32_16x16x32_bf16(afl[1][0], cbh[cur][0], a1, 0, 0, 0);
    a0 = __builtin_amdgcn_mfma_f32_16x16x32_bf16(afl[0][1], cbh[cur][1], a0, 0, 0, 0);
    a1 = __builtin_amdgcn_mfma_f32_16x16x32_bf16(afl[1][1], cbh[cur][1], a1, 0, 0, 0);
    // hi*lo
    a0 = __builtin_amdgcn_mfma_f32_16x16x32_bf16(afh[0][0], cbl[cur][0], a0, 0, 0, 0);
    a1 = __builtin_amdgcn_mfma_f32_16x16x32_bf16(afh[1][0], cbl[cur][0], a1, 0, 0, 0);
    a0 = __builtin_amdgcn_mfma_f32_16x16x32_bf16(afh[0][1], cbl[cur][1], a0, 0, 0, 0);
    a1 = __builtin_amdgcn_mfma_f32_16x16x32_bf16(afh[1][1], cbl[cur][1], a1, 0, 0, 0);

    const unsigned code = (unsigned)(cw0 + s * 16 + (lane & 15));
#pragma unroll
    for (int f = 0; f < 2; ++f) {
#pragma unroll
      for (int r = 0; r < 4; ++r) {
        float av = (f == 0) ? a0[r] : a1[r];
        float dist = fmaf(av, -2.0f, cesq[cur]);
        unsigned u = __float_as_uint(dist);
        unsigned sk = u ^ (unsigned)(((int)u >> 31) | 0x80000000);
        unsigned key = (sk & 0xFFFFFC00u) | code;
        unsigned t = umax_(b1[f][r], key);
        b1[f][r] = umin_(b1[f][r], key);
        b2[f][r] = umin_(b2[f][r], t);
      }
    }
  }
#undef LOADB

  // cross-lane top-2 merge across the 16 col-slots (lanes differing in bits 0..3)
#pragma unroll
  for (int m = 1; m < 16; m <<= 1) {
#pragma unroll
    for (int f = 0; f < 2; ++f)
#pragma unroll
      for (int r = 0; r < 4; ++r) {
        unsigned o1 = (unsigned)__shfl_xor((int)b1[f][r], m, 64);
        unsigned o2 = (unsigned)__shfl_xor((int)b2[f][r], m, 64);
        unsigned t = umax_(b1[f][r], o1);
        b1[f][r] = umin_(b1[f][r], o1);
        b2[f][r] = umin_(umin_(b2[f][r], o2), t);
      }
  }
  if ((lane & 15) == 0) {
    const int g = lane >> 4;
#pragma unroll
    for (int f = 0; f < 2; ++f)
#pragma unroll
      for (int r = 0; r < 4; ++r) {
        const int row = f * 16 + g * 4 + r;
        mrg1[wave][row] = b1[f][r];
        mrg2[wave][row] = b2[f][r];
      }
  }
  __syncthreads();

  // Phase 2: merge 4 wave-quadrants per row, f64 recheck near-ties, emit index
  if (tid < 32) {
    const int r = tid;
    unsigned B1 = 0xFFFFFFFFu, B2 = 0xFFFFFFFFu;
#pragma unroll
    for (int w = 0; w < 4; ++w) {
      unsigned o1 = mrg1[w][r], o2 = mrg2[w][r];
      unsigned t = umax_(B1, o1);
      B1 = umin_(B1, o1);
      B2 = umin_(umin_(B2, o2), t);
    }
    int i1 = (int)(B1 & 1023u);
    const int i2 = (int)(B2 & 1023u);
    // close call (within 8 quantization buckets) -> exact f64 decision
    if ((B2 & ~1023u) - (B1 & ~1023u) <= (8u << 10)) {
      double d1 = dist64row(zbase, r, emb_f32, i1);
      double d2 = dist64row(zbase, r, emb_f32, i2);
      if (d2 < d1 || (d2 == d1 && i2 < i1)) i1 = i2;
    }
    idx_sh[r] = i1;
    out[IDX_OFF + b * T_ + t0 + r] = (float)i1;
    atomicAdd(&counts[i1], 1);
  }
  __syncthreads();

  // Phase 3: gather z_q (exact f32), write out, exact commit-loss partial
  {
    const int r = tid & 31, d0 = (tid >> 5) * 8;
    const int k = idx_sh[r];
    const float* ep = emb_f32 + (size_t)k * D_ + d0;
    float c = 0.f;
#pragma unroll
    for (int j = 0; j < 8; ++j) {
      float e = ep[j];
      float x = zbase[(size_t)(d0 + j) * T_ + r];
      out[ZQ_OFF + ((size_t)b * D_ + d0 + j) * T_ + t0 + r] = e;
      float df = x - e;
      c = fmaf(df, df, c);
    }
    cred[tid] = c;
  }
  __syncthreads();
  for (int s = 128; s > 0; s >>= 1) {
    if (tid < s) cred[tid] += cred[tid + s];
    __syncthreads();
  }
  if (tid == 0) atomicAdd(commit_ws, cred[0]);
}

__global__ __launch_bounds__(1024) void finalize_kernel(
    const int* __restrict__ counts, const float* __restrict__ commit_ws,
    float* __restrict__ out) {
  __shared__ float red[1024];
  const int k = threadIdx.x;
  const int c = counts[k];
  const float p = (float)c / (float)BT_;
  out[HIST_OFF + k] = p;
  red[k] = (c > 0) ? p * logf(p) : 0.0f;
  __syncthreads();
  for (int s = 512; s > 0; s >>= 1) {
    if (k < s) red[k] += red[k + s];
    __syncthreads();
  }
  if (k == 0) {
    out[PERP_OFF] = expf(-red[0]);
    out[LOSS_OFF] = 0.25f * commit_ws[0] / (float)(B_ * D_ * T_);
  }
}

extern "C" void kernel_launch(void* const* d_in, const int* in_sizes, int n_in,
                              void* d_out, int out_size, void* d_ws, size_t ws_size,
                              hipStream_t stream) {
  const float* z_e = (const float*)d_in[0];
  const float* emb = (const float*)d_in[1];
  float* out = (float*)d_out;

  // ws layout (bytes): [0] counts int[1024]; [4096] commit f32;
  // [8192] e_sq f32[1024]; [12288] ebh ushort[65536]; [143360] ebl ushort[65536]
  int*   counts    = (int*)d_ws;
  float* commit_ws = (float*)((char*)d_ws + 4096);
  float* e_sq      = (float*)((char*)d_ws + 8192);
  ushort* ebh      = (ushort*)((char*)d_ws + 12288);
  ushort* ebl      = (ushort*)((char*)d_ws + 12288 + 131072);

  prep_kernel<<<16, 256, 0, stream>>>(emb, (int*)d_ws, e_sq, ebh, ebl);
  vq_mfma<<<BT_ / 32, 256, 0, stream>>>(z_e, emb, e_sq, ebh, ebl, out,
                                        commit_ws, counts);
  finalize_kernel<<<1, 1024, 0, stream>>>(counts, commit_ws, out);
}

// Round 11
// 144.877 us; speedup vs baseline: 1.2670x; 1.2670x over previous
//
#include <hip/hip_runtime.h>
#include <hip/hip_bf16.h>
#include <math.h>

#define B_ 16
#define D_ 64
#define T_ 4096
#define K_ 1024
#define BT_ (B_*T_)

// output layout (flat f32, concatenated in return order)
#define ZQ_OFF   0
#define LOSS_OFF 4194304
#define IDX_OFF  4194305
#define PERP_OFF 4259841
#define HIST_OFF 4259842

typedef __attribute__((ext_vector_type(8))) short bf16x8;
typedef __attribute__((ext_vector_type(4))) float f32x4;

__device__ __forceinline__ unsigned umin_(unsigned a, unsigned b){ return a < b ? a : b; }
__device__ __forceinline__ unsigned umax_(unsigned a, unsigned b){ return a > b ? a : b; }

__device__ __forceinline__ ushort f2bf(float x) {
  __hip_bfloat16 h = __float2bfloat16(x);
  return *(ushort*)&h;
}
__device__ __forceinline__ float bf2f(ushort u) {
  __hip_bfloat16 h; *(ushort*)&h = u;
  return __bfloat162float(h);
}

// ---- prep: zero counters + emb f32 -> (ebh, ebl) bf16 split + e_sq ----
__global__ __launch_bounds__(256) void prep_kernel(
    const float* __restrict__ emb, int* __restrict__ zero_ws,
    float* __restrict__ e_sq, ushort* __restrict__ ebh, ushort* __restrict__ ebl) {
  const int tid = blockIdx.x * 256 + threadIdx.x;
  if (tid < 1026) zero_ws[tid] = 0;   // counts[1024] + commit (+spare)
  const int k = tid >> 2, q = tid & 3;
  const float4* p = (const float4*)(emb + (size_t)k * D_ + q * 16);
  bf16x8 vh[2], vl[2];
  float s = 0.f;
#pragma unroll
  for (int i = 0; i < 4; ++i) {
    float4 v = p[i];
    float xs[4] = {v.x, v.y, v.z, v.w};
#pragma unroll
    for (int j = 0; j < 4; ++j) {
      float x = xs[j];
      ushort hb = f2bf(x);
      ushort lb = f2bf(x - bf2f(hb));
      vh[i >> 1][(i & 1) * 4 + j] = (short)hb;
      vl[i >> 1][(i & 1) * 4 + j] = (short)lb;
      s = fmaf(x, x, s);
    }
  }
  size_t off = (size_t)k * D_ + q * 16;
  *(bf16x8*)(ebh + off) = vh[0];
  *(bf16x8*)(ebh + off + 8) = vh[1];
  *(bf16x8*)(ebl + off) = vl[0];
  *(bf16x8*)(ebl + off + 8) = vl[1];
  s += __shfl_xor(s, 1, 64);
  s += __shfl_xor(s, 2, 64);
  if (q == 0) e_sq[k] = s;
}

// ---- main: 32 rows/block, 4 waves x 256-code quadrant, MFMA bf16-split ----
// Main loop identical to the measured 107us round-8 kernel. Phase 2 recheck is
// now wave-parallel: 8 threads per row (2 candidates x 4 dim-chunks) instead of
// 1 thread doing 2 serial 64-dim f64 gathers (the recheck fires ~every row:
// 8-bucket window 0.0625 >> typical top-2 gap ~3e-3).
__global__ __launch_bounds__(256) void vq_mfma(
    const float* __restrict__ z_e, const float* __restrict__ emb_f32,
    const float* __restrict__ e_sq, const ushort* __restrict__ ebh,
    const ushort* __restrict__ ebl, float* __restrict__ out,
    float* __restrict__ commit_ws, int* __restrict__ counts) {
  __shared__ ushort Ah[32 * 64];
  __shared__ ushort Al[32 * 64];
  __shared__ unsigned mrg1[4][32];
  __shared__ unsigned mrg2[4][32];
  __shared__ int cand_sh[32][2];
  __shared__ int idx_sh[32];
  __shared__ float cred[256];

  const int tid = threadIdx.x;
  const int lane = tid & 63, wave = tid >> 6;
  const int b = blockIdx.x >> 7;
  const int t0 = (blockIdx.x & 127) << 5;
  const float* zbase = z_e + ((size_t)b * D_) * T_ + t0;

  // Phase 0: stage A tile (32 rows x 64 d) as bf16 hi/lo, XOR-swizzled rows
  {
    const int r = tid & 31, d0 = (tid >> 5) * 8;
    bf16x8 vh, vl;
#pragma unroll
    for (int j = 0; j < 8; ++j) {
      float x = zbase[(size_t)(d0 + j) * T_ + r];
      ushort hb = f2bf(x);
      vh[j] = (short)hb;
      vl[j] = (short)f2bf(x - bf2f(hb));
    }
    const int off = (r * 128 + d0 * 2) ^ ((r & 7) << 4);  // byte offset
    *(bf16x8*)((char*)Ah + off) = vh;
    *(bf16x8*)((char*)Al + off) = vl;
  }
  __syncthreads();

  // A fragments to registers (reused across all 16 slabs): [rowfrag][kstep]
  bf16x8 afh[2][2], afl[2][2];
  {
    const int ar = lane & 15;
    const int aks = (lane >> 4) * 8;
#pragma unroll
    for (int f = 0; f < 2; ++f)
#pragma unroll
      for (int ks = 0; ks < 2; ++ks) {
        const int row = f * 16 + ar;
        const int col = ks * 32 + aks;
        const int off = (row * 128 + col * 2) ^ ((row & 7) << 4);
        afh[f][ks] = *(bf16x8*)((char*)Ah + off);
        afl[f][ks] = *(bf16x8*)((char*)Al + off);
      }
  }

  const int cw0 = wave * 256;  // wave's code base (wave-uniform)
  const size_t boff = (size_t)(cw0 + (lane & 15)) * D_ + (lane >> 4) * 8;

  unsigned b1[2][4], b2[2][4];
#pragma unroll
  for (int f = 0; f < 2; ++f)
#pragma unroll
    for (int r = 0; r < 4; ++r) { b1[f][r] = 0xFFFFFFFFu; b2[f][r] = 0xFFFFFFFFu; }

  bf16x8 cbh[2][2], cbl[2][2];
  float cesq[2];
#define LOADB(s, buf)                                                   \
  { size_t o = boff + (size_t)(s) * 16 * D_;                            \
    cbh[buf][0] = *(const bf16x8*)(ebh + o);                            \
    cbh[buf][1] = *(const bf16x8*)(ebh + o + 32);                       \
    cbl[buf][0] = *(const bf16x8*)(ebl + o);                            \
    cbl[buf][1] = *(const bf16x8*)(ebl + o + 32);                       \
    cesq[buf] = e_sq[cw0 + (s) * 16 + (lane & 15)]; }

  LOADB(0, 0);
#pragma unroll
  for (int s = 0; s < 16; ++s) {
    const int cur = s & 1, nxt = cur ^ 1;
    if (s < 15) LOADB(s + 1, nxt);
    f32x4 a0 = {0.f, 0.f, 0.f, 0.f}, a1 = {0.f, 0.f, 0.f, 0.f};
    // hi*hi (both ksteps)
    a0 = __builtin_amdgcn_mfma_f32_16x16x32_bf16(afh[0][0], cbh[cur][0], a0, 0, 0, 0);
    a1 = __builtin_amdgcn_mfma_f32_16x16x32_bf16(afh[1][0], cbh[cur][0], a1, 0, 0, 0);
    a0 = __builtin_amdgcn_mfma_f32_16x16x32_bf16(afh[0][1], cbh[cur][1], a0, 0, 0, 0);
    a1 = __builtin_amdgcn_mfma_f32_16x16x32_bf16(afh[1][1], cbh[cur][1], a1, 0, 0, 0);
    // lo*hi
    a0 = __builtin_amdgcn_mfma_f32_16x16x32_bf16(afl[0][0], cbh[cur][0], a0, 0, 0, 0);
    a1 = __builtin_amdgcn_mfma_f32_16x16x32_bf16(afl[1][0], cbh[cur][0], a1, 0, 0, 0);
    a0 = __builtin_amdgcn_mfma_f32_16x16x32_bf16(afl[0][1], cbh[cur][1], a0, 0, 0, 0);
    a1 = __builtin_amdgcn_mfma_f32_16x16x32_bf16(afl[1][1], cbh[cur][1], a1, 0, 0, 0);
    // hi*lo
    a0 = __builtin_amdgcn_mfma_f32_16x16x32_bf16(afh[0][0], cbl[cur][0], a0, 0, 0, 0);
    a1 = __builtin_amdgcn_mfma_f32_16x16x32_bf16(afh[1][0], cbl[cur][0], a1, 0, 0, 0);
    a0 = __builtin_amdgcn_mfma_f32_16x16x32_bf16(afh[0][1], cbl[cur][1], a0, 0, 0, 0);
    a1 = __builtin_amdgcn_mfma_f32_16x16x32_bf16(afh[1][1], cbl[cur][1], a1, 0, 0, 0);

    const unsigned code = (unsigned)(cw0 + s * 16 + (lane & 15));
#pragma unroll
    for (int f = 0; f < 2; ++f) {
#pragma unroll
      for (int r = 0; r < 4; ++r) {
        float av = (f == 0) ? a0[r] : a1[r];
        float dist = fmaf(av, -2.0f, cesq[cur]);
        unsigned u = __float_as_uint(dist);
        unsigned sk = u ^ (unsigned)(((int)u >> 31) | 0x80000000);
        unsigned key = (sk & 0xFFFFFC00u) | code;
        unsigned t = umax_(b1[f][r], key);
        b1[f][r] = umin_(b1[f][r], key);
        b2[f][r] = umin_(b2[f][r], t);
      }
    }
  }
#undef LOADB

  // cross-lane top-2 merge across the 16 col-slots (lanes differing in bits 0..3)
#pragma unroll
  for (int m = 1; m < 16; m <<= 1) {
#pragma unroll
    for (int f = 0; f < 2; ++f)
#pragma unroll
      for (int r = 0; r < 4; ++r) {
        unsigned o1 = (unsigned)__shfl_xor((int)b1[f][r], m, 64);
        unsigned o2 = (unsigned)__shfl_xor((int)b2[f][r], m, 64);
        unsigned t = umax_(b1[f][r], o1);
        b1[f][r] = umin_(b1[f][r], o1);
        b2[f][r] = umin_(umin_(b2[f][r], o2), t);
      }
  }
  if ((lane & 15) == 0) {
    const int g = lane >> 4;
#pragma unroll
    for (int f = 0; f < 2; ++f)
#pragma unroll
      for (int r = 0; r < 4; ++r) {
        const int row = f * 16 + g * 4 + r;
        mrg1[wave][row] = b1[f][r];
        mrg2[wave][row] = b2[f][r];
      }
  }
  __syncthreads();

  // Phase 2a (tid<32): merge 4 wave-quadrants per row -> top-2 candidates
  if (tid < 32) {
    const int r = tid;
    unsigned B1 = 0xFFFFFFFFu, B2 = 0xFFFFFFFFu;
#pragma unroll
    for (int w = 0; w < 4; ++w) {
      unsigned o1 = mrg1[w][r], o2 = mrg2[w][r];
      unsigned t = umax_(B1, o1);
      B1 = umin_(B1, o1);
      B2 = umin_(umin_(B2, o2), t);
    }
    cand_sh[r][0] = (int)(B1 & 1023u);
    cand_sh[r][1] = (int)(B2 & 1023u);
  }
  __syncthreads();

  // Phase 2b (all 256 threads): f64 decision between the two candidates.
  // 8 threads per row: cand = bit2, chunk = bits0..1 (16 dims each).
  {
    const int r = tid >> 3, cand = (tid >> 2) & 1, chunk = tid & 3;
    const int k = cand_sh[r][cand];
    const float4* ep = (const float4*)(emb_f32 + (size_t)k * D_ + chunk * 16);
    const float* xp = zbase + (size_t)(chunk * 16) * T_ + r;
    double sacc = 0.0;
#pragma unroll
    for (int q = 0; q < 4; ++q) {
      float4 ev = ep[q];
      float es[4] = {ev.x, ev.y, ev.z, ev.w};
#pragma unroll
      for (int j = 0; j < 4; ++j) {
        double e = (double)es[j];
        double x = (double)xp[(size_t)(q * 4 + j) * T_];
        sacc += e * e - 2.0 * x * e;
      }
    }
    sacc += __shfl_xor(sacc, 1, 64);
    sacc += __shfl_xor(sacc, 2, 64);
    const double dother = __shfl_xor(sacc, 4, 64);
    const int kother = __shfl_xor(k, 4, 64);
    if ((tid & 7) == 0) {   // cand==0 && chunk==0: d1=sacc(k), d2=dother(kother)
      int i1 = k;
      if (dother < sacc || (dother == sacc && kother < i1)) i1 = kother;
      idx_sh[r] = i1;
      out[IDX_OFF + b * T_ + t0 + r] = (float)i1;
      atomicAdd(&counts[i1], 1);
    }
  }
  __syncthreads();

  // Phase 3: gather z_q (exact f32), write out, exact commit-loss partial
  {
    const int r = tid & 31, d0 = (tid >> 5) * 8;
    const int k = idx_sh[r];
    const float* ep = emb_f32 + (size_t)k * D_ + d0;
    float c = 0.f;
#pragma unroll
    for (int j = 0; j < 8; ++j) {
      float e = ep[j];
      float x = zbase[(size_t)(d0 + j) * T_ + r];
      out[ZQ_OFF + ((size_t)b * D_ + d0 + j) * T_ + t0 + r] = e;
      float df = x - e;
      c = fmaf(df, df, c);
    }
    cred[tid] = c;
  }
  __syncthreads();
  for (int s = 128; s > 0; s >>= 1) {
    if (tid < s) cred[tid] += cred[tid + s];
    __syncthreads();
  }
  if (tid == 0) atomicAdd(commit_ws, cred[0]);
}

__global__ __launch_bounds__(1024) void finalize_kernel(
    const int* __restrict__ counts, const float* __restrict__ commit_ws,
    float* __restrict__ out) {
  __shared__ float red[1024];
  const int k = threadIdx.x;
  const int c = counts[k];
  const float p = (float)c / (float)BT_;
  out[HIST_OFF + k] = p;
  red[k] = (c > 0) ? p * logf(p) : 0.0f;
  __syncthreads();
  for (int s = 512; s > 0; s >>= 1) {
    if (k < s) red[k] += red[k + s];
    __syncthreads();
  }
  if (k == 0) {
    out[PERP_OFF] = expf(-red[0]);
    out[LOSS_OFF] = 0.25f * commit_ws[0] / (float)(B_ * D_ * T_);
  }
}

extern "C" void kernel_launch(void* const* d_in, const int* in_sizes, int n_in,
                              void* d_out, int out_size, void* d_ws, size_t ws_size,
                              hipStream_t stream) {
  const float* z_e = (const float*)d_in[0];
  const float* emb = (const float*)d_in[1];
  float* out = (float*)d_out;

  // ws layout (bytes): [0] counts int[1024]; [4096] commit f32;
  // [8192] e_sq f32[1024]; [12288] ebh ushort[65536]; [143360] ebl ushort[65536]
  int*   counts    = (int*)d_ws;
  float* commit_ws = (float*)((char*)d_ws + 4096);
  float* e_sq      = (float*)((char*)d_ws + 8192);
  ushort* ebh      = (ushort*)((char*)d_ws + 12288);
  ushort* ebl      = (ushort*)((char*)d_ws + 12288 + 131072);

  prep_kernel<<<16, 256, 0, stream>>>(emb, (int*)d_ws, e_sq, ebh, ebl);
  vq_mfma<<<BT_ / 32, 256, 0, stream>>>(z_e, emb, e_sq, ebh, ebl, out,
                                        commit_ws, counts);
  finalize_kernel<<<1, 1024, 0, stream>>>(counts, commit_ws, out);
}

// Round 12
// 119.464 us; speedup vs baseline: 1.5365x; 1.2127x over previous
//
#include <hip/hip_runtime.h>
#include <hip/hip_bf16.h>
#include <math.h>

#define B_ 16
#define D_ 64
#define T_ 4096
#define K_ 1024
#define BT_ (B_*T_)

// output layout (flat f32, concatenated in return order)
#define ZQ_OFF   0
#define LOSS_OFF 4194304
#define IDX_OFF  4194305
#define PERP_OFF 4259841
#define HIST_OFF 4259842

typedef __attribute__((ext_vector_type(8))) short bf16x8;
typedef __attribute__((ext_vector_type(4))) float f32x4;

__device__ __forceinline__ unsigned umin_(unsigned a, unsigned b){ return a < b ? a : b; }
__device__ __forceinline__ unsigned umax_(unsigned a, unsigned b){ return a > b ? a : b; }

__device__ __forceinline__ ushort f2bf(float x) {
  __hip_bfloat16 h = __float2bfloat16(x);
  return *(ushort*)&h;
}
__device__ __forceinline__ float bf2f(ushort u) {
  __hip_bfloat16 h; *(ushort*)&h = u;
  return __bfloat162float(h);
}

// ---- prep: zero counters + emb f32 -> (ebh, ebl) bf16 split + e_sq ----
__global__ __launch_bounds__(256) void prep_kernel(
    const float* __restrict__ emb, int* __restrict__ zero_ws,
    float* __restrict__ e_sq, ushort* __restrict__ ebh, ushort* __restrict__ ebl) {
  const int tid = blockIdx.x * 256 + threadIdx.x;
  if (tid < 1026) zero_ws[tid] = 0;   // counts[1024] + commit (+spare)
  const int k = tid >> 2, q = tid & 3;
  const float4* p = (const float4*)(emb + (size_t)k * D_ + q * 16);
  bf16x8 vh[2], vl[2];
  float s = 0.f;
#pragma unroll
  for (int i = 0; i < 4; ++i) {
    float4 v = p[i];
    float xs[4] = {v.x, v.y, v.z, v.w};
#pragma unroll
    for (int j = 0; j < 4; ++j) {
      float x = xs[j];
      ushort hb = f2bf(x);
      ushort lb = f2bf(x - bf2f(hb));
      vh[i >> 1][(i & 1) * 4 + j] = (short)hb;
      vl[i >> 1][(i & 1) * 4 + j] = (short)lb;
      s = fmaf(x, x, s);
    }
  }
  size_t off = (size_t)k * D_ + q * 16;
  *(bf16x8*)(ebh + off) = vh[0];
  *(bf16x8*)(ebh + off + 8) = vh[1];
  *(bf16x8*)(ebl + off) = vl[0];
  *(bf16x8*)(ebl + off + 8) = vl[1];
  s += __shfl_xor(s, 1, 64);
  s += __shfl_xor(s, 2, 64);
  if (q == 0) e_sq[k] = s;
}

// ---- main: 128 rows/block, 4 waves x 32 rows (M-split), B shared via LDS ----
// Each group = 4 slabs (64 codes) staged hi+lo (16 KB) into a double buffer;
// all 4 waves consume the same staged slabs (4x B-reuse vs the r11 K-split:
// L2 B-traffic 512 MB -> 128 MB). B LDS layout is XOR-swizzled:
//   linear slot (c, s') holds 16B chunk s = s'^(c&7) of code c
// so ds_read_b128 across lanes c=0..15 hits 8 distinct 16B slots (2-way = free).
// Stage-side writes use the same involution; numerics identical to r11.
__global__ __launch_bounds__(256) void vq_mfma(
    const float* __restrict__ z_e, const float* __restrict__ emb_f32,
    const float* __restrict__ e_sq, const ushort* __restrict__ ebh,
    const ushort* __restrict__ ebl, float* __restrict__ out,
    float* __restrict__ commit_ws, int* __restrict__ counts) {
  __shared__ ushort Ah[128 * 64];                 // 16 KB
  __shared__ ushort Al[128 * 64];                 // 16 KB
  __shared__ __align__(16) char Bbuf[2][16384];   // 32 KB: [hi 4x2KB][lo 4x2KB]
  __shared__ float esq_sh[1024];                  // 4 KB
  __shared__ float xsq_part[128][8];              // 4 KB
  __shared__ int   cand_sh[128][2];
  __shared__ int   idx_sh[128];
  __shared__ float cred_sh[4];

  const int tid = threadIdx.x;
  const int lane = tid & 63, wave = tid >> 6;
  const int b  = blockIdx.x >> 5;
  const int t0 = (blockIdx.x & 31) << 7;          // 128-row t-tile
  const float* zbase = z_e + ((size_t)b * D_) * T_ + t0;

  // Phase 0: stage A (128 rows x 64 dims) hi/lo + xsq parts; esq -> LDS.
  // unit = (r = tid&127 fixed per thread, dim-group g8); lanes consecutive in r.
  {
#pragma unroll
    for (int u = 0; u < 4; ++u) {
      const int unit = tid + 256 * u;
      const int r = unit & 127, g8 = unit >> 7;
      const int d0 = g8 * 8;
      bf16x8 vh, vl;
      float xs = 0.f;
#pragma unroll
      for (int j = 0; j < 8; ++j) {
        float x = zbase[(size_t)(d0 + j) * T_ + r];
        ushort hb = f2bf(x);
        vh[j] = (short)hb;
        vl[j] = (short)f2bf(x - bf2f(hb));
        xs = fmaf(x, x, xs);
      }
      const int off = (r * 128 + d0 * 2) ^ ((r & 7) << 4);
      *(bf16x8*)((char*)Ah + off) = vh;
      *(bf16x8*)((char*)Al + off) = vl;
      xsq_part[r][g8] = xs;
    }
    *(float4*)(esq_sh + tid * 4) = *(const float4*)(e_sq + tid * 4);
  }

  // stage-group helpers: wave w stages slab w of each group (hi 2KB + lo 2KB)
  bf16x8 sth0, sth1, stl0, stl1;
#define STAGE_LOAD(g)                                                         \
  { const int gg_ = (g);                                                      \
    { const int L = lane * 16;                                                \
      const int cp = L >> 7, sp = (L >> 4) & 7;                               \
      const size_t so = ((size_t)(gg_ * 64 + wave * 16 + cp)) * 64            \
                        + (size_t)((sp ^ (cp & 7)) * 8);                      \
      sth0 = *(const bf16x8*)(ebh + so); stl0 = *(const bf16x8*)(ebl + so); } \
    { const int L = 1024 + lane * 16;                                         \
      const int cp = L >> 7, sp = (L >> 4) & 7;                               \
      const size_t so = ((size_t)(gg_ * 64 + wave * 16 + cp)) * 64            \
                        + (size_t)((sp ^ (cp & 7)) * 8);                      \
      sth1 = *(const bf16x8*)(ebh + so); stl1 = *(const bf16x8*)(ebl + so); } }
#define STAGE_WRITE(bi)                                                       \
  { char* bb = Bbuf[bi] + wave * 2048;                                        \
    *(bf16x8*)(bb + lane * 16) = sth0;                                        \
    *(bf16x8*)(bb + 1024 + lane * 16) = sth1;                                 \
    *(bf16x8*)(bb + 8192 + lane * 16) = stl0;                                 \
    *(bf16x8*)(bb + 8192 + 1024 + lane * 16) = stl1; }

  STAGE_LOAD(0);
  __syncthreads();            // A, xsq, esq ready

  // A fragments (per wave: its own 32 rows), reused for all 64 slabs
  bf16x8 afh[2][2], afl[2][2];
  {
    const int ar = lane & 15, aks = (lane >> 4) * 8;
#pragma unroll
    for (int f = 0; f < 2; ++f)
#pragma unroll
      for (int ks = 0; ks < 2; ++ks) {
        const int row = wave * 32 + f * 16 + ar;
        const int col = ks * 32 + aks;
        const int off = (row * 128 + col * 2) ^ ((row & 7) << 4);
        afh[f][ks] = *(bf16x8*)((char*)Ah + off);
        afl[f][ks] = *(bf16x8*)((char*)Al + off);
      }
  }
  STAGE_WRITE(0);
  __syncthreads();            // Bbuf[0] ready

  unsigned b1[2][4], b2[2][4];
#pragma unroll
  for (int f = 0; f < 2; ++f)
#pragma unroll
    for (int r = 0; r < 4; ++r) { b1[f][r] = 0xFFFFFFFFu; b2[f][r] = 0xFFFFFFFFu; }

  int cur = 0;
  for (int g = 0; g < 16; ++g) {
    if (g < 15) STAGE_LOAD(g + 1);     // loads in flight over this group's compute
#pragma unroll
    for (int ss = 0; ss < 4; ++ss) {
      const char* hb = Bbuf[cur] + ss * 2048;
      const char* lb = hb + 8192;
      const int c = lane & 15, kc = lane >> 4;
      bf16x8 cb_h[2], cb_l[2];
#pragma unroll
      for (int ks = 0; ks < 2; ++ks) {
        const int s = ks * 4 + kc;
        const int off = c * 128 + ((s ^ (c & 7)) << 4);
        cb_h[ks] = *(const bf16x8*)(hb + off);
        cb_l[ks] = *(const bf16x8*)(lb + off);
      }
      const float ces = esq_sh[g * 64 + ss * 16 + c];
      f32x4 a0 = {0.f, 0.f, 0.f, 0.f}, a1 = {0.f, 0.f, 0.f, 0.f};
      // hi*hi (both ksteps) — same sequence as r11 for bitwise-equal acc
      a0 = __builtin_amdgcn_mfma_f32_16x16x32_bf16(afh[0][0], cb_h[0], a0, 0, 0, 0);
      a1 = __builtin_amdgcn_mfma_f32_16x16x32_bf16(afh[1][0], cb_h[0], a1, 0, 0, 0);
      a0 = __builtin_amdgcn_mfma_f32_16x16x32_bf16(afh[0][1], cb_h[1], a0, 0, 0, 0);
      a1 = __builtin_amdgcn_mfma_f32_16x16x32_bf16(afh[1][1], cb_h[1], a1, 0, 0, 0);
      // lo*hi
      a0 = __builtin_amdgcn_mfma_f32_16x16x32_bf16(afl[0][0], cb_h[0], a0, 0, 0, 0);
      a1 = __builtin_amdgcn_mfma_f32_16x16x32_bf16(afl[1][0], cb_h[0], a1, 0, 0, 0);
      a0 = __builtin_amdgcn_mfma_f32_16x16x32_bf16(afl[0][1], cb_h[1], a0, 0, 0, 0);
      a1 = __builtin_amdgcn_mfma_f32_16x16x32_bf16(afl[1][1], cb_h[1], a1, 0, 0, 0);
      // hi*lo
      a0 = __builtin_amdgcn_mfma_f32_16x16x32_bf16(afh[0][0], cb_l[0], a0, 0, 0, 0);
      a1 = __builtin_amdgcn_mfma_f32_16x16x32_bf16(afh[1][0], cb_l[0], a1, 0, 0, 0);
      a0 = __builtin_amdgcn_mfma_f32_16x16x32_bf16(afh[0][1], cb_l[1], a0, 0, 0, 0);
      a1 = __builtin_amdgcn_mfma_f32_16x16x32_bf16(afh[1][1], cb_l[1], a1, 0, 0, 0);

      const unsigned code = (unsigned)(g * 64 + ss * 16 + c);
#pragma unroll
      for (int f = 0; f < 2; ++f) {
#pragma unroll
        for (int r = 0; r < 4; ++r) {
          float av = (f == 0) ? a0[r] : a1[r];
          float dist = fmaf(av, -2.0f, ces);
          unsigned u = __float_as_uint(dist);
          unsigned sk = u ^ (unsigned)(((int)u >> 31) | 0x80000000);
          unsigned key = (sk & 0xFFFFFC00u) | code;
          unsigned t = umax_(b1[f][r], key);
          b1[f][r] = umin_(b1[f][r], key);
          b2[f][r] = umin_(b2[f][r], t);
        }
      }
    }
    if (g < 15) STAGE_WRITE(cur ^ 1);  // write other buffer (nobody reads it yet)
    __syncthreads();                   // all reads of cur done + nxt staged
    cur ^= 1;
  }
#undef STAGE_LOAD
#undef STAGE_WRITE

  // per-wave top-2 merge across the 16 col-slots (lane bits 0..3)
#pragma unroll
  for (int m = 1; m < 16; m <<= 1) {
#pragma unroll
    for (int f = 0; f < 2; ++f)
#pragma unroll
      for (int r = 0; r < 4; ++r) {
        unsigned o1 = (unsigned)__shfl_xor((int)b1[f][r], m, 64);
        unsigned o2 = (unsigned)__shfl_xor((int)b2[f][r], m, 64);
        unsigned t = umax_(b1[f][r], o1);
        b1[f][r] = umin_(b1[f][r], o1);
        b2[f][r] = umin_(umin_(b2[f][r], o2), t);
      }
  }
  if ((lane & 15) == 0) {
    const int g4 = lane >> 4;
#pragma unroll
    for (int f = 0; f < 2; ++f)
#pragma unroll
      for (int r = 0; r < 4; ++r) {
        const int row = wave * 32 + f * 16 + g4 * 4 + r;
        cand_sh[row][0] = (int)(b1[f][r] & 1023u);
        cand_sh[row][1] = (int)(b2[f][r] & 1023u);
      }
  }
  __syncthreads();

  // Phase 2b: exact f64 decision, 2 threads/row (one per candidate).
  // Also produces the commit contribution: c = x^2 + (e^2 - 2xe)_win.
  {
    const int r = tid >> 1, cand = tid & 1;
    const int k = cand_sh[r][cand];
    const float* ep = emb_f32 + (size_t)k * D_;
    const float* xp = zbase + r;
    double sacc = 0.0;
#pragma unroll 8
    for (int d = 0; d < D_; ++d) {
      const double e = (double)ep[d];
      const double x = (double)xp[(size_t)d * T_];
      sacc += e * e - 2.0 * x * e;
    }
    const double so = __shfl_xor(sacc, 1, 64);
    const int ko = __shfl_xor(k, 1, 64);
    float cc = 0.f;
    if (cand == 0) {
      int win = k; double dwin = sacc;
      if (so < sacc || (so == sacc && ko < k)) { win = ko; dwin = so; }
      idx_sh[r] = win;
      out[IDX_OFF + b * T_ + t0 + r] = (float)win;
      atomicAdd(&counts[win], 1);
      float xs = 0.f;
#pragma unroll
      for (int g8 = 0; g8 < 8; ++g8) xs += xsq_part[r][g8];
      cc = xs + (float)dwin;
    }
#pragma unroll
    for (int m = 1; m < 64; m <<= 1) cc += __shfl_xor(cc, m, 64);
    if (lane == 0) cred_sh[wave] = cc;
  }
  __syncthreads();

  // Phase 3: gather z_q (exact f32) and write; commit atomic once per block
  {
    const int r = tid & 127, dh = tid >> 7;
    const int k = idx_sh[r];
    const float4* ep = (const float4*)(emb_f32 + (size_t)k * D_ + dh * 32);
    float* op = out + ZQ_OFF + ((size_t)(b * D_ + dh * 32)) * T_ + t0 + r;
#pragma unroll
    for (int q = 0; q < 8; ++q) {
      float4 v = ep[q];
      op[(size_t)(q * 4 + 0) * T_] = v.x;
      op[(size_t)(q * 4 + 1) * T_] = v.y;
      op[(size_t)(q * 4 + 2) * T_] = v.z;
      op[(size_t)(q * 4 + 3) * T_] = v.w;
    }
  }
  if (tid == 0)
    atomicAdd(commit_ws, cred_sh[0] + cred_sh[1] + cred_sh[2] + cred_sh[3]);
}

__global__ __launch_bounds__(1024) void finalize_kernel(
    const int* __restrict__ counts, const float* __restrict__ commit_ws,
    float* __restrict__ out) {
  __shared__ float red[1024];
  const int k = threadIdx.x;
  const int c = counts[k];
  const float p = (float)c / (float)BT_;
  out[HIST_OFF + k] = p;
  red[k] = (c > 0) ? p * logf(p) : 0.0f;
  __syncthreads();
  for (int s = 512; s > 0; s >>= 1) {
    if (k < s) red[k] += red[k + s];
    __syncthreads();
  }
  if (k == 0) {
    out[PERP_OFF] = expf(-red[0]);
    out[LOSS_OFF] = 0.25f * commit_ws[0] / (float)(B_ * D_ * T_);
  }
}

extern "C" void kernel_launch(void* const* d_in, const int* in_sizes, int n_in,
                              void* d_out, int out_size, void* d_ws, size_t ws_size,
                              hipStream_t stream) {
  const float* z_e = (const float*)d_in[0];
  const float* emb = (const float*)d_in[1];
  float* out = (float*)d_out;

  // ws layout (bytes): [0] counts int[1024]; [4096] commit f32;
  // [8192] e_sq f32[1024]; [12288] ebh ushort[65536]; [143360] ebl ushort[65536]
  int*   counts    = (int*)d_ws;
  float* commit_ws = (float*)((char*)d_ws + 4096);
  float* e_sq      = (float*)((char*)d_ws + 8192);
  ushort* ebh      = (ushort*)((char*)d_ws + 12288);
  ushort* ebl      = (ushort*)((char*)d_ws + 12288 + 131072);

  prep_kernel<<<16, 256, 0, stream>>>(emb, (int*)d_ws, e_sq, ebh, ebl);
  vq_mfma<<<BT_ / 128, 256, 0, stream>>>(z_e, emb, e_sq, ebh, ebl, out,
                                         commit_ws, counts);
  finalize_kernel<<<1, 1024, 0, stream>>>(counts, commit_ws, out);
}